// Round 1
// baseline (263.166 us; speedup 1.0000x reference)
//
#include <hip/hip_runtime.h>
#include <math.h>

#define N 2048
#define E 65536
#define EMBED 64
#define H 128
#define NT 20
#define C3 320   /* EMBED + H + H */
#define SLOPE 0.01f

__device__ __forceinline__ float leaky(float x) { return x > 0.f ? x : SLOPE * x; }

__device__ __forceinline__ float wave_sum(float v) {
#pragma unroll
    for (int o = 32; o > 0; o >>= 1) v += __shfl_xor(v, o, 64);
    return v;
}

// ---------------- graph preprocessing ----------------
__global__ void k_gather(const int* __restrict__ ids, const float* __restrict__ emb,
                         float* __restrict__ x) {
    int i = blockIdx.x * blockDim.x + threadIdx.x;
    if (i < N * EMBED) {
        int n = i >> 6, c = i & 63;
        x[i] = emb[ids[n] * EMBED + c];
    }
}

__global__ void k_hist(const int* __restrict__ ei, int* __restrict__ counts) {
    int e = blockIdx.x * blockDim.x + threadIdx.x;
    if (e < E) atomicAdd(&counts[ei[E + e]], 1);
}

__global__ void k_scan(const int* __restrict__ counts, int* __restrict__ offsets) {
    __shared__ int tot[256];
    int tid = threadIdx.x;
    int base = tid * 8;
    int loc[8];
    int s = 0;
#pragma unroll
    for (int k = 0; k < 8; k++) { loc[k] = s; s += counts[base + k]; }
    tot[tid] = s;
    __syncthreads();
    for (int off = 1; off < 256; off <<= 1) {
        int add = (tid >= off) ? tot[tid - off] : 0;
        __syncthreads();
        tot[tid] += add;
        __syncthreads();
    }
    int excl = tot[tid] - s;  // exclusive prefix of this chunk
#pragma unroll
    for (int k = 0; k < 8; k++) offsets[base + k] = excl + loc[k];
    if (tid == 255) offsets[N] = tot[255];
}

__global__ void k_scatter(const int* __restrict__ ei, const int* __restrict__ offsets,
                          int* __restrict__ cursor, int* __restrict__ eorder) {
    int e = blockIdx.x * blockDim.x + threadIdx.x;
    if (e < E) {
        int d = ei[E + e];
        int p = offsets[d] + atomicAdd(&cursor[d], 1);
        eorder[p] = e;
    }
}

// ---------------- weight transposes (coalesced inner loops) ----------------
// WT[c*H + k] = W[k*stride + c], c < IN
__global__ void k_transpose(const float* __restrict__ W, float* __restrict__ WT,
                            int IN, int stride) {
    int i = blockIdx.x * blockDim.x + threadIdx.x;
    if (i < IN * H) {
        int c = i / H, k = i % H;
        WT[i] = W[k * stride + c];
    }
}

// W1T[c*NT + t] = W1[t*640 + c], c < 640
__global__ void k_transposeW1(const float* __restrict__ W1, float* __restrict__ W1T) {
    int i = blockIdx.x * blockDim.x + threadIdx.x;
    if (i < 2 * C3 * NT) {
        int c = i / NT, t = i % NT;
        W1T[i] = W1[t * (2 * C3) + c];
    }
}

// ---------------- small dense layers ----------------
// out[n][k] = (relu?)( dot(xin[n,:IN], WT[:,k]) + bias[k] ), WT is [IN][H] c-major
template <int IN>
__global__ __launch_bounds__(H) void k_lin(const float* __restrict__ xin,
                                           const float* __restrict__ WT,
                                           const float* __restrict__ bias,
                                           float* __restrict__ out, int do_relu) {
    int n = blockIdx.x;
    int k = threadIdx.x;  // 128
    __shared__ float xs[IN];
    if (k < IN) xs[k] = xin[n * IN + k];
    __syncthreads();
    float acc = bias ? bias[k] : 0.f;
#pragma unroll 8
    for (int c = 0; c < IN; c++) acc = fmaf(xs[c], WT[c * H + k], acc);
    if (do_relu) acc = fmaxf(acc, 0.f);
    out[n * H + k] = acc;
}

// ---------------- GATE conv aggregation: one wave per dst node ----------------
__global__ __launch_bounds__(64) void k_gate(
    const float* __restrict__ xin, int D,          // layer input [N][D]
    const float* __restrict__ A,                   // [N][H] = xin @ lin1[:, :D].T
    const float* __restrict__ lin1, int stride,    // last col = edge-attr weight
    const float* __restrict__ att_l, const float* __restrict__ att_r,
    const float* __restrict__ eattr, const int* __restrict__ srcrow,
    const int* __restrict__ offsets, const int* __restrict__ eorder,
    float* __restrict__ agg) {
    int dst = blockIdx.x;
    int lane = threadIdx.x;  // 64

    float p = 0.f;
    for (int c = lane; c < D; c += 64) p += xin[dst * D + c] * att_r[c];
    float xr = wave_sum(p);

    float attl0 = att_l[lane], attl1 = att_l[lane + 64];
    float w0 = lin1[lane * stride + D];
    float w1 = lin1[(lane + 64) * stride + D];

    int o0 = offsets[dst], o1 = offsets[dst + 1];
    float mmax = -INFINITY, s = 0.f, v0 = 0.f, v1 = 0.f;
    for (int i = o0; i < o1; i++) {
        int e = eorder[i];
        int sn = srcrow[e];
        float ea = eattr[e];
        float h0 = leaky(fmaf(w0, ea, A[sn * H + lane]));
        float h1 = leaky(fmaf(w1, ea, A[sn * H + 64 + lane]));
        float alpha = leaky(wave_sum(h0 * attl0 + h1 * attl1) + xr);
        if (alpha > mmax) {  // wave-uniform branch
            float f = __expf(mmax - alpha);  // first iter: exp(-inf) = 0
            s *= f; v0 *= f; v1 *= f;
            mmax = alpha;
        }
        float w = __expf(alpha - mmax);
        s += w;
        v0 = fmaf(w, h0, v0);
        v1 = fmaf(w, h1, v1);
    }
    float inv = 1.f / (s + 1e-16f);
    agg[dst * H + lane] = v0 * inv;
    agg[dst * H + 64 + lane] = v1 * inv;
}

// ---------------- pairwise head: a/b projections ----------------
__global__ __launch_bounds__(64) void k_ab(const float* __restrict__ x,
                                           const float* __restrict__ h1,
                                           const float* __restrict__ h2,
                                           const float* __restrict__ W1T,
                                           float* __restrict__ aArr,
                                           float* __restrict__ bT) {
    int n = blockIdx.x;
    int tid = threadIdx.x;  // 64
    __shared__ float fs[C3];
    for (int c = tid; c < EMBED; c += 64) fs[c] = x[n * EMBED + c];
    for (int c = tid; c < H; c += 64) {
        fs[EMBED + c] = h1[n * H + c];
        fs[EMBED + H + c] = h2[n * H + c];
    }
    __syncthreads();
    if (tid < 2 * NT) {
        int t = tid < NT ? tid : tid - NT;
        int cb = tid < NT ? 0 : C3;
        float acc = 0.f;
#pragma unroll 8
        for (int c = 0; c < C3; c++) acc = fmaf(fs[c], W1T[(cb + c) * NT + t], acc);
        if (tid < NT) aArr[n * NT + t] = acc;
        else bT[t * N + n] = acc;
    }
}

// ---------------- final: logits + row softmax, 4 rows per block ----------------
__global__ __launch_bounds__(256) void k_final(const float* __restrict__ aArr,
                                               const float* __restrict__ bT,
                                               const float* __restrict__ b1,
                                               const float* __restrict__ W2,
                                               const float* __restrict__ b2,
                                               const float* __restrict__ mmat,
                                               float* __restrict__ out) {
    __shared__ float lg[4][N];    // 32 KB
    __shared__ float ash[4][NT];
    __shared__ float red[256];
    int i0 = blockIdx.x * 4;
    int tid = threadIdx.x;
    if (tid < 4 * NT) {
        int g = tid / NT, t = tid % NT;
        ash[g][t] = aArr[(i0 + g) * NT + t];
    }
    __syncthreads();
    float w2r[NT], b1r[NT];
#pragma unroll
    for (int t = 0; t < NT; t++) { w2r[t] = W2[t]; b1r[t] = b1[t]; }
    float b2v = b2[0];

    for (int j = tid; j < N; j += 256) {
        float bt[NT];
#pragma unroll
        for (int t = 0; t < NT; t++) bt[t] = bT[t * N + j];
#pragma unroll
        for (int g = 0; g < 4; g++) {
            float l = b2v;
#pragma unroll
            for (int t = 0; t < NT; t++)
                l += fmaxf(ash[g][t] + bt[t] + b1r[t], 0.f) * w2r[t];
            l *= mmat[(size_t)(i0 + g) * N + j];
            lg[g][j] = l;
        }
    }
    __syncthreads();

#pragma unroll 1
    for (int g = 0; g < 4; g++) {
        float pm = -INFINITY;
        for (int j = tid; j < N; j += 256) pm = fmaxf(pm, lg[g][j]);
        red[tid] = pm;
        __syncthreads();
        for (int o = 128; o > 0; o >>= 1) {
            if (tid < o) red[tid] = fmaxf(red[tid], red[tid + o]);
            __syncthreads();
        }
        float mx = red[0];
        __syncthreads();
        float ps = 0.f;
        for (int j = tid; j < N; j += 256) {
            float pv = __expf(lg[g][j] - mx);
            lg[g][j] = pv;
            ps += pv;
        }
        red[tid] = ps;
        __syncthreads();
        for (int o = 128; o > 0; o >>= 1) {
            if (tid < o) red[tid] += red[tid + o];
            __syncthreads();
        }
        float inv = 1.f / red[0];
        __syncthreads();
        for (int j = tid; j < N; j += 256) out[(size_t)(i0 + g) * N + j] = lg[g][j] * inv;
    }
}

extern "C" void kernel_launch(void* const* d_in, const int* in_sizes, int n_in,
                              void* d_out, int out_size, void* d_ws, size_t ws_size,
                              hipStream_t stream) {
    const int*   node_ids = (const int*)d_in[0];
    const int*   ei       = (const int*)d_in[1];   // [2][E]: row0 = src, row1 = dst
    const float* eattr    = (const float*)d_in[2];
    const float* mmat     = (const float*)d_in[3];
    const float* emb      = (const float*)d_in[4];
    const float* l0_lin1  = (const float*)d_in[5];
    const float* l0_lin2  = (const float*)d_in[6];
    const float* l0_att_l = (const float*)d_in[7];
    const float* l0_att_r = (const float*)d_in[8];
    const float* l0_bias  = (const float*)d_in[9];
    const float* l1_lin1  = (const float*)d_in[10];
    const float* l1_lin2  = (const float*)d_in[11];
    const float* l1_att_l = (const float*)d_in[12];
    const float* l1_att_r = (const float*)d_in[13];
    const float* l1_bias  = (const float*)d_in[14];
    const float* W1       = (const float*)d_in[15];
    const float* b1       = (const float*)d_in[16];
    const float* W2       = (const float*)d_in[17];
    const float* b2       = (const float*)d_in[18];
    float* out = (float*)d_out;

    char* w = (char*)d_ws;
    auto alloc = [&](size_t bytes) {
        char* p = w;
        w += (bytes + 255) & ~(size_t)255;
        return p;
    };
    int* counts  = (int*)alloc(2 * N * sizeof(int));  // counts + cursor, contiguous
    int* cursor  = counts + N;
    int* offsets = (int*)alloc((N + 1) * sizeof(int));
    int* eorder  = (int*)alloc(E * sizeof(int));
    float* x    = (float*)alloc(N * EMBED * sizeof(float));
    float* A    = (float*)alloc(N * H * sizeof(float));
    float* agg  = (float*)alloc(N * H * sizeof(float));
    float* h1   = (float*)alloc(N * H * sizeof(float));
    float* h2   = (float*)alloc(N * H * sizeof(float));
    float* aArr = (float*)alloc(N * NT * sizeof(float));
    float* bT   = (float*)alloc(NT * N * sizeof(float));
    float* WT0  = (float*)alloc(EMBED * H * sizeof(float));
    float* WT1  = (float*)alloc(H * H * sizeof(float));
    float* LT0  = (float*)alloc(H * H * sizeof(float));
    float* LT1  = (float*)alloc(H * H * sizeof(float));
    float* W1T  = (float*)alloc(2 * C3 * NT * sizeof(float));

    hipMemsetAsync(counts, 0, 2 * N * sizeof(int), stream);

    k_gather<<<(N * EMBED + 255) / 256, 256, 0, stream>>>(node_ids, emb, x);
    k_hist<<<E / 256, 256, 0, stream>>>(ei, counts);
    k_scan<<<1, 256, 0, stream>>>(counts, offsets);
    k_scatter<<<E / 256, 256, 0, stream>>>(ei, offsets, cursor, eorder);

    k_transpose<<<(EMBED * H + 255) / 256, 256, 0, stream>>>(l0_lin1, WT0, EMBED, EMBED + 1);
    k_transpose<<<(H * H + 255) / 256, 256, 0, stream>>>(l1_lin1, WT1, H, H + 1);
    k_transpose<<<(H * H + 255) / 256, 256, 0, stream>>>(l0_lin2, LT0, H, H);
    k_transpose<<<(H * H + 255) / 256, 256, 0, stream>>>(l1_lin2, LT1, H, H);
    k_transposeW1<<<(2 * C3 * NT + 255) / 256, 256, 0, stream>>>(W1, W1T);

    // layer 0
    k_lin<EMBED><<<N, H, 0, stream>>>(x, WT0, nullptr, A, 0);
    k_gate<<<N, 64, 0, stream>>>(x, EMBED, A, l0_lin1, EMBED + 1, l0_att_l, l0_att_r,
                                 eattr, ei, offsets, eorder, agg);
    k_lin<H><<<N, H, 0, stream>>>(agg, LT0, l0_bias, h1, 1);
    // layer 1
    k_lin<H><<<N, H, 0, stream>>>(h1, WT1, nullptr, A, 0);
    k_gate<<<N, 64, 0, stream>>>(h1, H, A, l1_lin1, H + 1, l1_att_l, l1_att_r,
                                 eattr, ei, offsets, eorder, agg);
    k_lin<H><<<N, H, 0, stream>>>(agg, LT1, l1_bias, h2, 1);

    // head
    k_ab<<<N, 64, 0, stream>>>(x, h1, h2, W1T, aArr, bT);
    k_final<<<N / 4, 256, 0, stream>>>(aArr, bT, b1, W2, b2, mmat, out);
}

// Round 2
// 200.641 us; speedup vs baseline: 1.3116x; 1.3116x over previous
//
#include <hip/hip_runtime.h>
#include <math.h>

#define N 2048
#define E 65536
#define EMBED 64
#define H 128
#define NT 20
#define C3 320   /* EMBED + H + H */
#define SLOPE 0.01f

__device__ __forceinline__ float leaky(float x) { return x > 0.f ? x : SLOPE * x; }

__device__ __forceinline__ float wave_sum(float v) {
#pragma unroll
    for (int o = 32; o > 0; o >>= 1) v += __shfl_xor(v, o, 64);
    return v;
}

// ---------------- prep: zero counts/cursor + all weight transposes ----------------
// segment map (element index i):
//   [0,4096)                 zero counts+cursor
//   [4096,12288)             WT0[c*128+k]  = l0_lin1[k*65+c]   (c<64)
//   [12288,28672)            WT1[c*128+k]  = l1_lin1[k*129+c]  (c<128)
//   [28672,45056)            LT0[c*128+k]  = l0_lin2[k*128+c]
//   [45056,61440)            LT1[c*128+k]  = l1_lin2[k*128+c]
//   [61440,74240)            W1T[c*20+t]   = W1[t*640+c]       (c<640)
__global__ void k_prep(int* __restrict__ counts,
                       const float* __restrict__ l0_lin1, float* __restrict__ WT0,
                       const float* __restrict__ l1_lin1, float* __restrict__ WT1,
                       const float* __restrict__ l0_lin2, float* __restrict__ LT0,
                       const float* __restrict__ l1_lin2, float* __restrict__ LT1,
                       const float* __restrict__ W1,      float* __restrict__ W1T) {
    int i = blockIdx.x * blockDim.x + threadIdx.x;
    if (i < 4096) {
        counts[i] = 0;
    } else if (i < 12288) {
        int j = i - 4096; int c = j >> 7, k = j & 127;
        WT0[j] = l0_lin1[k * (EMBED + 1) + c];
    } else if (i < 28672) {
        int j = i - 12288; int c = j >> 7, k = j & 127;
        WT1[j] = l1_lin1[k * (H + 1) + c];
    } else if (i < 45056) {
        int j = i - 28672; int c = j >> 7, k = j & 127;
        LT0[j] = l0_lin2[k * H + c];
    } else if (i < 61440) {
        int j = i - 45056; int c = j >> 7, k = j & 127;
        LT1[j] = l1_lin2[k * H + c];
    } else if (i < 74240) {
        int j = i - 61440; int c = j / NT, t = j % NT;
        W1T[j] = W1[t * (2 * C3) + c];
    }
}

__global__ void k_hist(const int* __restrict__ ei, int* __restrict__ counts) {
    int e = blockIdx.x * blockDim.x + threadIdx.x;
    if (e < E) atomicAdd(&counts[ei[E + e]], 1);
}

__global__ void k_scan(const int* __restrict__ counts, int* __restrict__ offsets) {
    __shared__ int tot[256];
    int tid = threadIdx.x;
    int base = tid * 8;
    int loc[8];
    int s = 0;
#pragma unroll
    for (int k = 0; k < 8; k++) { loc[k] = s; s += counts[base + k]; }
    tot[tid] = s;
    __syncthreads();
    for (int off = 1; off < 256; off <<= 1) {
        int add = (tid >= off) ? tot[tid - off] : 0;
        __syncthreads();
        tot[tid] += add;
        __syncthreads();
    }
    int excl = tot[tid] - s;
#pragma unroll
    for (int k = 0; k < 8; k++) offsets[base + k] = excl + loc[k];
    if (tid == 255) offsets[N] = tot[255];
}

// scatter edges into dst-sorted order, materializing reordered src + eattr
__global__ void k_scatter(const int* __restrict__ ei, const float* __restrict__ eattr,
                          const int* __restrict__ offsets, int* __restrict__ cursor,
                          int* __restrict__ srcs, float* __restrict__ eas) {
    int e = blockIdx.x * blockDim.x + threadIdx.x;
    if (e < E) {
        int d = ei[E + e];
        int p = offsets[d] + atomicAdd(&cursor[d], 1);
        srcs[p] = ei[e];
        eas[p] = eattr[e];
    }
}

// ---------------- layer-0 input: gather x row + A0 = x @ lin1[:, :64].T ----------------
__global__ __launch_bounds__(H) void k_lin0(const int* __restrict__ ids,
                                            const float* __restrict__ emb,
                                            const float* __restrict__ WT0,
                                            float* __restrict__ x,
                                            float* __restrict__ A) {
    int n = blockIdx.x;
    int k = threadIdx.x;  // 128
    __shared__ float xs[EMBED];
    if (k < EMBED) {
        float v = emb[ids[n] * EMBED + k];
        xs[k] = v;
        x[n * EMBED + k] = v;
    }
    __syncthreads();
    float a0 = 0.f, a1 = 0.f;
#pragma unroll 8
    for (int c = 0; c < EMBED; c += 2) {
        a0 = fmaf(xs[c], WT0[c * H + k], a0);
        a1 = fmaf(xs[c + 1], WT0[(c + 1) * H + k], a1);
    }
    A[n * H + k] = a0 + a1;
}

// ---------------- GATE conv aggregation: 4 waves per dst, partial online softmax ----------------
__global__ __launch_bounds__(256) void k_gate(
    const float* __restrict__ xin, int D,
    const float* __restrict__ A,
    const float* __restrict__ lin1, int stride,
    const float* __restrict__ att_l, const float* __restrict__ att_r,
    const int* __restrict__ srcs, const float* __restrict__ eas,
    const int* __restrict__ offsets,
    float* __restrict__ agg) {
    int dst = blockIdx.x;
    int tid = threadIdx.x;
    int wv = tid >> 6, lane = tid & 63;

    float p = 0.f;
    for (int c = lane; c < D; c += 64) p += xin[dst * D + c] * att_r[c];
    float xr = wave_sum(p);

    float attl0 = att_l[lane], attl1 = att_l[lane + 64];
    float w0 = lin1[lane * stride + D];
    float w1 = lin1[(lane + 64) * stride + D];

    int o0 = offsets[dst], o1 = offsets[dst + 1];
    float mmax = -INFINITY, s = 0.f, v0 = 0.f, v1 = 0.f;

    int i = o0 + wv;
    int sn = 0; float ea = 0.f, a0 = 0.f, a1 = 0.f;
    if (i < o1) {
        sn = srcs[i]; ea = eas[i];
        a0 = A[sn * H + lane]; a1 = A[sn * H + 64 + lane];
    }
    while (i < o1) {
        int i2 = i + 4;
        int sn2 = 0; float ea2 = 0.f, p0 = 0.f, p1 = 0.f;
        bool has2 = i2 < o1;
        if (has2) {
            sn2 = srcs[i2]; ea2 = eas[i2];
            p0 = A[sn2 * H + lane]; p1 = A[sn2 * H + 64 + lane];
        }
        float h0 = leaky(fmaf(w0, ea, a0));
        float h1 = leaky(fmaf(w1, ea, a1));
        float alpha = leaky(wave_sum(h0 * attl0 + h1 * attl1) + xr);
        float mnew = fmaxf(mmax, alpha);
        float scale = __expf(mmax - mnew);   // first iter: exp(-inf) = 0
        float wgt = __expf(alpha - mnew);
        s = fmaf(s, scale, wgt);
        v0 = fmaf(wgt, h0, v0 * scale);
        v1 = fmaf(wgt, h1, v1 * scale);
        mmax = mnew;
        i = i2; sn = sn2; ea = ea2; a0 = p0; a1 = p1;
    }

    __shared__ float msh[4], ssh[4], vsh[4][H];
    if (lane == 0) { msh[wv] = mmax; ssh[wv] = s; }
    vsh[wv][lane] = v0;
    vsh[wv][64 + lane] = v1;
    __syncthreads();
    if (tid < H) {
        float mM = fmaxf(fmaxf(msh[0], msh[1]), fmaxf(msh[2], msh[3]));
        float stot = 0.f, vtot = 0.f;
#pragma unroll
        for (int w = 0; w < 4; w++) {
            float sc = (ssh[w] > 0.f) ? __expf(msh[w] - mM) : 0.f;
            stot = fmaf(ssh[w], sc, stot);
            vtot = fmaf(vsh[w][tid], sc, vtot);
        }
        agg[dst * H + tid] = vtot / (stot + 1e-16f);
    }
}

// ---------------- fused: h1 = relu(agg0@LT0+b0); A1 = h1@WT1 ----------------
__global__ __launch_bounds__(H) void k_lin1(const float* __restrict__ agg0,
                                            const float* __restrict__ LT0,
                                            const float* __restrict__ b0,
                                            const float* __restrict__ WT1,
                                            float* __restrict__ h1,
                                            float* __restrict__ A) {
    int n = blockIdx.x;
    int k = threadIdx.x;  // 128
    __shared__ float s0[H], s1[H];
    s0[k] = agg0[n * H + k];
    __syncthreads();
    float t0 = b0[k], t1 = 0.f;
#pragma unroll 8
    for (int c = 0; c < H; c += 2) {
        t0 = fmaf(s0[c], LT0[c * H + k], t0);
        t1 = fmaf(s0[c + 1], LT0[(c + 1) * H + k], t1);
    }
    float hv = fmaxf(t0 + t1, 0.f);
    h1[n * H + k] = hv;
    s1[k] = hv;
    __syncthreads();
    float u0 = 0.f, u1 = 0.f;
#pragma unroll 8
    for (int c = 0; c < H; c += 2) {
        u0 = fmaf(s1[c], WT1[c * H + k], u0);
        u1 = fmaf(s1[c + 1], WT1[(c + 1) * H + k], u1);
    }
    A[n * H + k] = u0 + u1;
}

// ---------------- tail: h2 = relu(agg1@LT1+b); a/b projections ----------------
__global__ __launch_bounds__(H) void k_tail(const float* __restrict__ agg1,
                                            const float* __restrict__ LT1,
                                            const float* __restrict__ bL1,
                                            const float* __restrict__ x,
                                            const float* __restrict__ h1,
                                            const float* __restrict__ W1T,
                                            float* __restrict__ aArr,
                                            float* __restrict__ bT) {
    int n = blockIdx.x;
    int k = threadIdx.x;  // 128
    __shared__ float sg[H];
    __shared__ float feat[C3];
    sg[k] = agg1[n * H + k];
    if (k < EMBED) feat[k] = x[n * EMBED + k];
    feat[EMBED + k] = h1[n * H + k];
    __syncthreads();
    float t0 = bL1[k], t1 = 0.f;
#pragma unroll 8
    for (int c = 0; c < H; c += 2) {
        t0 = fmaf(sg[c], LT1[c * H + k], t0);
        t1 = fmaf(sg[c + 1], LT1[(c + 1) * H + k], t1);
    }
    feat[EMBED + H + k] = fmaxf(t0 + t1, 0.f);
    __syncthreads();
    if (k < 2 * NT) {
        int t = k < NT ? k : k - NT;
        int cb = k < NT ? 0 : C3;
        float acc = 0.f;
#pragma unroll 8
        for (int c = 0; c < C3; c++) acc = fmaf(feat[c], W1T[(cb + c) * NT + t], acc);
        if (k < NT) aArr[n * NT + t] = acc;
        else bT[t * N + n] = acc;
    }
}

// ---------------- final: logits + row softmax, 4 rows/block, online max ----------------
__global__ __launch_bounds__(256) void k_final(const float* __restrict__ aArr,
                                               const float* __restrict__ bT,
                                               const float* __restrict__ b1,
                                               const float* __restrict__ W2,
                                               const float* __restrict__ b2,
                                               const float* __restrict__ mmat,
                                               float* __restrict__ out) {
    __shared__ float lg[4][N];    // 32 KB
    __shared__ float ash[4][NT];
    __shared__ float red[16];
    int i0 = blockIdx.x * 4;
    int tid = threadIdx.x;
    int wv = tid >> 6;
    if (tid < 4 * NT) ash[tid / NT][tid % NT] = aArr[i0 * NT + tid];
    float w2r[NT], b1r[NT];
#pragma unroll
    for (int t = 0; t < NT; t++) { w2r[t] = W2[t]; b1r[t] = b1[t]; }
    float b2v = b2[0];
    __syncthreads();

    float tmax[4] = {-INFINITY, -INFINITY, -INFINITY, -INFINITY};
    for (int j = tid; j < N; j += 256) {
        float bt[NT];
#pragma unroll
        for (int t = 0; t < NT; t++) bt[t] = bT[t * N + j];
#pragma unroll
        for (int g = 0; g < 4; g++) {
            float l = b2v;
#pragma unroll
            for (int t = 0; t < NT; t++)
                l += fmaxf(ash[g][t] + bt[t] + b1r[t], 0.f) * w2r[t];
            l *= mmat[(size_t)(i0 + g) * N + j];
            lg[g][j] = l;
            tmax[g] = fmaxf(tmax[g], l);
        }
    }
    // block max per g: wave-shuffle then 4-wave LDS merge
#pragma unroll
    for (int g = 0; g < 4; g++) {
#pragma unroll
        for (int o = 32; o > 0; o >>= 1) tmax[g] = fmaxf(tmax[g], __shfl_xor(tmax[g], o, 64));
    }
    if ((tid & 63) == 0) {
#pragma unroll
        for (int g = 0; g < 4; g++) red[wv * 4 + g] = tmax[g];
    }
    __syncthreads();
    float mfin[4];
#pragma unroll
    for (int g = 0; g < 4; g++)
        mfin[g] = fmaxf(fmaxf(red[g], red[4 + g]), fmaxf(red[8 + g], red[12 + g]));
    __syncthreads();

    float ts[4] = {0.f, 0.f, 0.f, 0.f};
    for (int j = tid; j < N; j += 256) {
#pragma unroll
        for (int g = 0; g < 4; g++) {
            float e = __expf(lg[g][j] - mfin[g]);
            lg[g][j] = e;
            ts[g] += e;
        }
    }
#pragma unroll
    for (int g = 0; g < 4; g++) {
#pragma unroll
        for (int o = 32; o > 0; o >>= 1) ts[g] += __shfl_xor(ts[g], o, 64);
    }
    if ((tid & 63) == 0) {
#pragma unroll
        for (int g = 0; g < 4; g++) red[wv * 4 + g] = ts[g];
    }
    __syncthreads();
    float inv[4];
#pragma unroll
    for (int g = 0; g < 4; g++)
        inv[g] = 1.f / (red[g] + red[4 + g] + red[8 + g] + red[12 + g]);

    for (int j = tid; j < N; j += 256) {
#pragma unroll
        for (int g = 0; g < 4; g++)
            out[(size_t)(i0 + g) * N + j] = lg[g][j] * inv[g];
    }
}

extern "C" void kernel_launch(void* const* d_in, const int* in_sizes, int n_in,
                              void* d_out, int out_size, void* d_ws, size_t ws_size,
                              hipStream_t stream) {
    const int*   node_ids = (const int*)d_in[0];
    const int*   ei       = (const int*)d_in[1];   // [2][E]: row0 = src, row1 = dst
    const float* eattr    = (const float*)d_in[2];
    const float* mmat     = (const float*)d_in[3];
    const float* emb      = (const float*)d_in[4];
    const float* l0_lin1  = (const float*)d_in[5];
    const float* l0_lin2  = (const float*)d_in[6];
    const float* l0_att_l = (const float*)d_in[7];
    const float* l0_att_r = (const float*)d_in[8];
    const float* l0_bias  = (const float*)d_in[9];
    const float* l1_lin1  = (const float*)d_in[10];
    const float* l1_lin2  = (const float*)d_in[11];
    const float* l1_att_l = (const float*)d_in[12];
    const float* l1_att_r = (const float*)d_in[13];
    const float* l1_bias  = (const float*)d_in[14];
    const float* W1       = (const float*)d_in[15];
    const float* b1       = (const float*)d_in[16];
    const float* W2       = (const float*)d_in[17];
    const float* b2       = (const float*)d_in[18];
    float* out = (float*)d_out;

    char* w = (char*)d_ws;
    auto alloc = [&](size_t bytes) {
        char* p = w;
        w += (bytes + 255) & ~(size_t)255;
        return p;
    };
    int* counts  = (int*)alloc(2 * N * sizeof(int));  // counts + cursor, contiguous
    int* cursor  = counts + N;
    int* offsets = (int*)alloc((N + 1) * sizeof(int));
    int* srcs    = (int*)alloc(E * sizeof(int));
    float* eas   = (float*)alloc(E * sizeof(float));
    float* x    = (float*)alloc(N * EMBED * sizeof(float));
    float* A    = (float*)alloc(N * H * sizeof(float));
    float* agg  = (float*)alloc(N * H * sizeof(float));
    float* h1   = (float*)alloc(N * H * sizeof(float));
    float* aArr = (float*)alloc(N * NT * sizeof(float));
    float* bT   = (float*)alloc(NT * N * sizeof(float));
    float* WT0  = (float*)alloc(EMBED * H * sizeof(float));
    float* WT1  = (float*)alloc(H * H * sizeof(float));
    float* LT0  = (float*)alloc(H * H * sizeof(float));
    float* LT1  = (float*)alloc(H * H * sizeof(float));
    float* W1T  = (float*)alloc(2 * C3 * NT * sizeof(float));

    k_prep<<<(74240 + 255) / 256, 256, 0, stream>>>(counts, l0_lin1, WT0, l1_lin1, WT1,
                                                    l0_lin2, LT0, l1_lin2, LT1, W1, W1T);
    k_hist<<<E / 256, 256, 0, stream>>>(ei, counts);
    k_scan<<<1, 256, 0, stream>>>(counts, offsets);
    k_scatter<<<E / 256, 256, 0, stream>>>(ei, eattr, offsets, cursor, srcs, eas);

    // layer 0
    k_lin0<<<N, H, 0, stream>>>(node_ids, emb, WT0, x, A);
    k_gate<<<N, 256, 0, stream>>>(x, EMBED, A, l0_lin1, EMBED + 1, l0_att_l, l0_att_r,
                                  srcs, eas, offsets, agg);
    // layer 1 input
    k_lin1<<<N, H, 0, stream>>>(agg, LT0, l0_bias, WT1, h1, A);
    k_gate<<<N, 256, 0, stream>>>(h1, H, A, l1_lin1, H + 1, l1_att_l, l1_att_r,
                                  srcs, eas, offsets, agg);
    // tail: h2 + projections
    k_tail<<<N, H, 0, stream>>>(agg, LT1, l1_bias, x, h1, W1T, aArr, bT);
    // head
    k_final<<<N / 4, 256, 0, stream>>>(aArr, bT, b1, W2, b2, mmat, out);
}